// Round 1
// baseline (1163.817 us; speedup 1.0000x reference)
//
#include <hip/hip_runtime.h>
#include <math.h>

#define BATCH 32
#define NH 32
#define NKVH 8
#define GQ 4
#define DIM 128
#define KMAX 4096
#define HS 4096
#define SCALE 0.08838834764831843f   /* 128^-0.5 */
#define SK 8            /* GEMM k-split */
#define KCHUNK 512      /* 4096/SK */
#define SA 16           /* attention kv-split */
#define ACHUNK 256      /* 4096/SA */

// ---------------------------------------------------------------------------
// Split-K skinny GEMM: Cpart[sk][b][j] = sum_{k in chunk sk} A[b][k] * W[j][k]
// A: (32, 4096) row-major, W: (4096, 4096) row-major (we need A @ W^T).
// Grid (32 j-tiles, SK), block 256. Each thread: 2 b x 8 j accumulators.
// W staged to LDS transposed [k][j] with XOR swizzle at float4 granularity
// (conflict-free b128 reads); A staged transposed [k][b] with +1 pad
// (broadcast reads).
// ---------------------------------------------------------------------------
__global__ __launch_bounds__(256) void gemm_part_kernel(
    const float* __restrict__ A, const float* __restrict__ W,
    float* __restrict__ Cp)
{
  __shared__ float As[64 * 33];     // [k][b], stride 33 (pad)
  __shared__ float Ws[64 * 128];    // [k][j], XOR-swizzled float4 blocks
  const int t  = threadIdx.x;
  const int jt = blockIdx.x;
  const int sk = blockIdx.y;
  const int j0 = jt * 128;
  const int kc = sk * KCHUNK;
  const int tj = t & 15;            // j group: j = 4*tj..+3 and 64+4*tj..+3
  const int tb = t >> 4;            // b group: b = 2*tb, 2*tb+1
  const int b0 = tb * 2;

  float acc[2][8];
#pragma unroll
  for (int i = 0; i < 2; ++i)
#pragma unroll
    for (int j = 0; j < 8; ++j) acc[i][j] = 0.f;

  for (int kt = 0; kt < KCHUNK / 64; ++kt) {
    const int kbase = kc + kt * 64;
    __syncthreads();
    // stage A tile: 32 b x 64 k  (coalesced float4 global reads)
#pragma unroll
    for (int it = 0; it < 2; ++it) {
      int idx = t + 256 * it;           // 0..511
      int b = idx >> 4, kq = idx & 15;
      float4 v = *(const float4*)&A[(size_t)b * HS + kbase + kq * 4];
      As[(4 * kq + 0) * 33 + b] = v.x;
      As[(4 * kq + 1) * 33 + b] = v.y;
      As[(4 * kq + 2) * 33 + b] = v.z;
      As[(4 * kq + 3) * 33 + b] = v.w;
    }
    // stage W tile: 128 j x 64 k (coalesced), write transposed + swizzled
#pragma unroll
    for (int it = 0; it < 8; ++it) {
      int idx = t + 256 * it;           // 0..2047
      int j = idx >> 4, kq = idx & 15;
      float4 v = *(const float4*)&W[(size_t)(j0 + j) * HS + kbase + kq * 4];
      int jb = j >> 2, jr = j & 3;
      int kb = 4 * kq;
      Ws[(kb + 0) * 128 + (((jb ^ ((kb + 0) & 31)) << 2) | jr)] = v.x;
      Ws[(kb + 1) * 128 + (((jb ^ ((kb + 1) & 31)) << 2) | jr)] = v.y;
      Ws[(kb + 2) * 128 + (((jb ^ ((kb + 2) & 31)) << 2) | jr)] = v.z;
      Ws[(kb + 3) * 128 + (((jb ^ ((kb + 3) & 31)) << 2) | jr)] = v.w;
    }
    __syncthreads();
#pragma unroll
    for (int kk = 0; kk < 64; ++kk) {
      float a0 = As[kk * 33 + b0];
      float a1 = As[kk * 33 + b0 + 1];
      int x = kk & 31;
      const float4 w0 = *(const float4*)&Ws[kk * 128 + ((tj ^ x) << 2)];
      const float4 w1 = *(const float4*)&Ws[kk * 128 + (((tj + 16) ^ x) << 2)];
      acc[0][0] += a0 * w0.x; acc[0][1] += a0 * w0.y;
      acc[0][2] += a0 * w0.z; acc[0][3] += a0 * w0.w;
      acc[0][4] += a0 * w1.x; acc[0][5] += a0 * w1.y;
      acc[0][6] += a0 * w1.z; acc[0][7] += a0 * w1.w;
      acc[1][0] += a1 * w0.x; acc[1][1] += a1 * w0.y;
      acc[1][2] += a1 * w0.z; acc[1][3] += a1 * w0.w;
      acc[1][4] += a1 * w1.x; acc[1][5] += a1 * w1.y;
      acc[1][6] += a1 * w1.z; acc[1][7] += a1 * w1.w;
    }
  }
#pragma unroll
  for (int i = 0; i < 2; ++i) {
    int b = b0 + i;
    float4 o0 = make_float4(acc[i][0], acc[i][1], acc[i][2], acc[i][3]);
    float4 o1 = make_float4(acc[i][4], acc[i][5], acc[i][6], acc[i][7]);
    *(float4*)&Cp[(size_t)(sk * BATCH + b) * HS + j0 + 4 * tj] = o0;
    *(float4*)&Cp[(size_t)(sk * BATCH + b) * HS + j0 + 64 + 4 * tj] = o1;
  }
}

// ---------------------------------------------------------------------------
// Combine GEMM partials for q + RoPE + fold in attention SCALE.
// One 64-lane block per (b, head). Lane d handles pair (d, d+64).
// ---------------------------------------------------------------------------
__global__ __launch_bounds__(64) void rope_kernel(
    const float* __restrict__ qp, const int* __restrict__ positions,
    float* __restrict__ qr)
{
  int bid  = blockIdx.x;            // b*NH + hh
  int b    = bid >> 5;
  int hh   = bid & 31;
  int lane = threadIdx.x;           // 0..63
  float q1 = 0.f, q2 = 0.f;
#pragma unroll
  for (int sk = 0; sk < SK; ++sk) {
    const float* p = qp + (size_t)(sk * BATCH + b) * HS + hh * DIM;
    q1 += p[lane];
    q2 += p[lane + 64];
  }
  float pos = (float)positions[b];
  float inv = powf(1.0e6f, -(float)lane * (1.0f / 64.0f));
  float ang = pos * inv;
  float s, c;
  sincosf(ang, &s, &c);
  qr[(size_t)bid * DIM + lane]      = (q1 * c - q2 * s) * SCALE;
  qr[(size_t)bid * DIM + lane + 64] = (q2 * c + q1 * s) * SCALE;
}

// ---------------------------------------------------------------------------
// Flash-decode attention partial: one block per (b, kvh, kv-chunk).
// 4 waves stride the chunk by 4 rows; lane holds d = {2*lane, 2*lane+1}.
// Online softmax per g (4 query heads share this KV head). Wave partials
// merged via LDS; chunk partial (m, l, unnormalized O) written to ws.
// ---------------------------------------------------------------------------
__global__ __launch_bounds__(256) void attn_part_kernel(
    const float* __restrict__ qr, const float* __restrict__ kcache,
    const float* __restrict__ vcache, const int* __restrict__ clens,
    float* __restrict__ pm, float* __restrict__ pl, float* __restrict__ pO)
{
  const int bid = blockIdx.x;       // b*(NKVH*SA) + h*SA + c
  const int c   = bid & (SA - 1);
  const int h   = (bid >> 4) & (NKVH - 1);
  const int b   = bid >> 7;
  const int L   = clens[b];
  const int k0  = c * ACHUNK;
  if (k0 >= L) return;              // uniform: whole block exits together
  const int kend = min(k0 + ACHUNK, L);
  const int t    = threadIdx.x;
  const int w    = t >> 6;
  const int lane = t & 63;

  float2 q[GQ];
#pragma unroll
  for (int g = 0; g < GQ; ++g)
    q[g] = *(const float2*)&qr[(size_t)(b * NH + h * GQ + g) * DIM + 2 * lane];

  float2 O[GQ];
  float m[GQ], l[GQ];
#pragma unroll
  for (int g = 0; g < GQ; ++g) {
    O[g] = make_float2(0.f, 0.f);
    m[g] = -INFINITY;
    l[g] = 0.f;
  }

  const size_t hoff = (size_t)h * DIM + 2 * lane;
  const float* Kb = kcache + (size_t)b * KMAX * NKVH * DIM + hoff;
  const float* Vb = vcache + (size_t)b * KMAX * NKVH * DIM + hoff;

  int k = k0 + w;
  float2 kv = make_float2(0.f, 0.f), vv = make_float2(0.f, 0.f);
  if (k < kend) {
    size_t off = (size_t)k * (NKVH * DIM);
    kv = *(const float2*)&Kb[off];
    vv = *(const float2*)&Vb[off];
  }
  for (; k < kend; k += 4) {
    // 1-deep prefetch of next row pair to keep 2 iters of loads in flight
    float2 kv_n = make_float2(0.f, 0.f), vv_n = make_float2(0.f, 0.f);
    int kn = k + 4;
    if (kn < kend) {
      size_t off = (size_t)kn * (NKVH * DIM);
      kv_n = *(const float2*)&Kb[off];
      vv_n = *(const float2*)&Vb[off];
    }
    float s[GQ];
#pragma unroll
    for (int g = 0; g < GQ; ++g) s[g] = q[g].x * kv.x + q[g].y * kv.y;
#pragma unroll
    for (int sh = 32; sh > 0; sh >>= 1) {
#pragma unroll
      for (int g = 0; g < GQ; ++g) s[g] += __shfl_xor(s[g], sh, 64);
    }
#pragma unroll
    for (int g = 0; g < GQ; ++g) {
      float mn = fmaxf(m[g], s[g]);
      float al = __expf(m[g] - mn);   // exp(-inf)=0 on first iter
      float p  = __expf(s[g] - mn);
      l[g]   = l[g] * al + p;
      O[g].x = O[g].x * al + p * vv.x;
      O[g].y = O[g].y * al + p * vv.y;
      m[g]   = mn;
    }
    kv = kv_n;
    vv = vv_n;
  }

  __shared__ float sm[4][GQ], sl[4][GQ];
  __shared__ float sO[4][GQ][DIM];
#pragma unroll
  for (int g = 0; g < GQ; ++g) {
    sO[w][g][2 * lane]     = O[g].x;
    sO[w][g][2 * lane + 1] = O[g].y;
  }
  if (lane == 0) {
#pragma unroll
    for (int g = 0; g < GQ; ++g) { sm[w][g] = m[g]; sl[w][g] = l[g]; }
  }
  __syncthreads();
  if (w == 0) {
#pragma unroll
    for (int g = 0; g < GQ; ++g) {
      float M = fmaxf(fmaxf(sm[0][g], sm[1][g]), fmaxf(sm[2][g], sm[3][g]));
      float Ls = 0.f, ox = 0.f, oy = 0.f;
#pragma unroll
      for (int ww = 0; ww < 4; ++ww) {
        float e = __expf(sm[ww][g] - M);  // empty wave: m=-inf -> e=0
        Ls += sl[ww][g] * e;
        ox += sO[ww][g][2 * lane] * e;
        oy += sO[ww][g][2 * lane + 1] * e;
      }
      size_t idx = (size_t)((b * NKVH + h) * GQ + g) * SA + c;
      if (lane == 0) { pm[idx] = M; pl[idx] = Ls; }
      *(float2*)&pO[idx * DIM + 2 * lane] = make_float2(ox, oy);
    }
  }
}

// ---------------------------------------------------------------------------
// Merge attention chunk partials with log-sum-exp; normalize; write attn out
// in (B, H*D) layout. One 128-thread block per (b, kvh, g) row.
// ---------------------------------------------------------------------------
__global__ __launch_bounds__(128) void attn_combine_kernel(
    const float* __restrict__ pm, const float* __restrict__ pl,
    const float* __restrict__ pO, const int* __restrict__ clens,
    float* __restrict__ attn)
{
  int row = blockIdx.x;             // (b*NKVH+h)*GQ+g
  int b   = row >> 5;
  int d   = threadIdx.x;            // 0..127
  int L   = clens[b];
  int nch = min(SA, (L + ACHUNK - 1) / ACHUNK);
  float M = -INFINITY;
  for (int c2 = 0; c2 < nch; ++c2) M = fmaxf(M, pm[(size_t)row * SA + c2]);
  float Ls = 0.f, o = 0.f;
  for (int c2 = 0; c2 < nch; ++c2) {
    float e = __expf(pm[(size_t)row * SA + c2] - M);
    Ls += pl[(size_t)row * SA + c2] * e;
    o  += pO[((size_t)row * SA + c2) * DIM + d] * e;
  }
  attn[(size_t)b * HS + (row & 31) * DIM + d] = o / Ls;
}

// ---------------------------------------------------------------------------
// Sum SK GEMM partials into final output.
// ---------------------------------------------------------------------------
__global__ __launch_bounds__(256) void sum_parts_kernel(
    const float* __restrict__ Op, float* __restrict__ out)
{
  int i = blockIdx.x * 256 + threadIdx.x;   // 0..131071
  float s = 0.f;
#pragma unroll
  for (int sk = 0; sk < SK; ++sk) s += Op[(size_t)sk * BATCH * HS + i];
  out[i] = s;
}

extern "C" void kernel_launch(void* const* d_in, const int* in_sizes, int n_in,
                              void* d_out, int out_size, void* d_ws, size_t ws_size,
                              hipStream_t stream)
{
  const float* hidden    = (const float*)d_in[0];
  const int*   positions = (const int*)d_in[1];
  const float* kcache    = (const float*)d_in[2];
  const float* vcache    = (const float*)d_in[3];
  const int*   clens     = (const int*)d_in[4];
  const float* wq        = (const float*)d_in[5];
  const float* wo        = (const float*)d_in[6];
  float* out = (float*)d_out;

  // workspace layout (floats); total ~3.44M floats (~13.8 MB)
  float* ws    = (float*)d_ws;
  float* qpart = ws;                                   // SK*32*4096 = 1048576
  float* qr    = qpart + (size_t)SK * BATCH * HS;      // 131072
  float* pm    = qr + (size_t)BATCH * HS;              // 16384
  float* pl    = pm + (size_t)BATCH * NKVH * GQ * SA;  // 16384
  float* pO    = pl + (size_t)BATCH * NKVH * GQ * SA;  // 2097152
  float* attn  = pO + (size_t)BATCH * NKVH * GQ * SA * DIM; // 131072
  float* opart = qpart;   // reuse: qpart dead after rope_kernel

  dim3 ggrid(HS / 128, SK);
  gemm_part_kernel<<<ggrid, 256, 0, stream>>>(hidden, wq, qpart);
  rope_kernel<<<BATCH * NH, 64, 0, stream>>>(qpart, positions, qr);
  attn_part_kernel<<<BATCH * NKVH * SA, 256, 0, stream>>>(
      qr, kcache, vcache, clens, pm, pl, pO);
  attn_combine_kernel<<<BATCH * NKVH * GQ, DIM, 0, stream>>>(
      pm, pl, pO, clens, attn);
  gemm_part_kernel<<<ggrid, 256, 0, stream>>>(attn, wo, opart);
  sum_parts_kernel<<<BATCH * HS / 256, 256, 0, stream>>>(opart, out);
}